// Round 2
// baseline (276.035 us; speedup 1.0000x reference)
//
#include <hip/hip_runtime.h>
#include <math.h>

#define QN 8192
#define SN 32768
#define EN 131072
#define DN 256
#define HN 8
#define HDN 32
#define GEON 128
#define FFNN 512

typedef __attribute__((ext_vector_type(8))) short bf16x8;
typedef __attribute__((ext_vector_type(8))) unsigned short u16x8;
typedef __attribute__((ext_vector_type(4))) unsigned short u16x4;
typedef __attribute__((ext_vector_type(4))) float f32x4;

__device__ __forceinline__ unsigned short f2b(float f) {
  union { float f; unsigned u; } v; v.f = f;
  unsigned u = v.u;
  u += 0x7fffu + ((u >> 16) & 1u);   // round-to-nearest-even
  return (unsigned short)(u >> 16);
}
__device__ __forceinline__ float b2f(unsigned short h) {
  union { unsigned u; float f; } v; v.u = ((unsigned)h) << 16; return v.f;
}
__device__ __forceinline__ float gelu_f(float x) {
  return 0.5f * x * (1.0f + erff(x * 0.70710678118654752440f));
}

// XOR swizzle in 8-element groups: phys_g = g ^ (row&7). Staging writes and
// fragment reads both land at the b128 minimum aliasing (conflict-free).
template <int KT>
__device__ __forceinline__ u16x8* lds_gk(unsigned short* base, int row, int col) {
  int g = (col >> 3) ^ (row & 7);
  return reinterpret_cast<u16x8*>(base + row * KT + g * 8);
}

// ---------------- tiled transpose: fp32 [K,N] -> bf16 [N,K] ----------------
__global__ __launch_bounds__(256) void transpose_weights(
    const float* Wq, const float* Wk, const float* Wv, const float* Wg,
    const float* Wo, const float* Wf1, const float* Wf2,
    unsigned short* WqT, unsigned short* WkvT, unsigned short* WgT,
    unsigned short* WoT, unsigned short* Wf1T, unsigned short* Wf2T) {
  int b = blockIdx.x;
  const float* src; unsigned short* dst; int K, N, tile;
  if (b < 16)       { src = Wq;  dst = WqT;          K = 256; N = 256; tile = b; }
  else if (b < 32)  { src = Wk;  dst = WkvT;         K = 256; N = 256; tile = b - 16; }
  else if (b < 48)  { src = Wv;  dst = WkvT + 65536; K = 256; N = 256; tile = b - 32; }
  else if (b < 56)  { src = Wg;  dst = WgT;          K = 128; N = 256; tile = b - 48; }
  else if (b < 72)  { src = Wo;  dst = WoT;          K = 256; N = 256; tile = b - 56; }
  else if (b < 104) { src = Wf1; dst = Wf1T;         K = 256; N = 512; tile = b - 72; }
  else              { src = Wf2; dst = Wf2T;         K = 512; N = 256; tile = b - 104; }
  int ktiles = K >> 6;
  int k0 = (tile % ktiles) * 64, n0 = (tile / ktiles) * 64;
  __shared__ float ts[64][65];
  int t = threadIdx.x;
  int c4 = (t & 15) * 4;
  int r = t >> 4;
#pragma unroll
  for (int p = 0; p < 4; ++p) {
    int row = p * 16 + r;
    float4 v = *(const float4*)(src + (size_t)(k0 + row) * N + n0 + c4);
    ts[row][c4 + 0] = v.x; ts[row][c4 + 1] = v.y;
    ts[row][c4 + 2] = v.z; ts[row][c4 + 3] = v.w;
  }
  __syncthreads();
#pragma unroll
  for (int p = 0; p < 4; ++p) {
    int n = p * 16 + r;
    ushort4 o;
    o.x = f2b(ts[c4 + 0][n]); o.y = f2b(ts[c4 + 1][n]);
    o.z = f2b(ts[c4 + 2][n]); o.w = f2b(ts[c4 + 3][n]);
    *(ushort4*)(dst + (size_t)(n0 + n) * K + k0 + c4) = o;
  }
}

// ---------------- segment offsets from sorted q_idx ----------------
__global__ __launch_bounds__(256) void seg_offsets(const int* q_idx, int* offs) {
  int i = blockIdx.x * 256 + threadIdx.x;
  if (i > QN) return;
  int lo = 0, hi = EN;
  while (lo < hi) {
    int mid = (lo + hi) >> 1;
    if (q_idx[mid] < i) lo = mid + 1; else hi = mid;
  }
  offs[i] = lo;
}

// ---------------- per-query geo stats -> raw [Q,12] ----------------
__global__ __launch_bounds__(256) void geo_stats_kernel(
    const float* qpos, const float* spos, const int* offs, const int* s_idx, float* raw) {
  int q = blockIdx.x * 64 + (threadIdx.x >> 2);
  int sub = threadIdx.x & 3;
  int e0 = offs[q], e1 = offs[q + 1];
  float qx = qpos[q * 3 + 0], qy = qpos[q * 3 + 1], qz = qpos[q * 3 + 2];
  float cnt = 0.f, sx = 0.f, sy = 0.f, sz = 0.f, sxx = 0.f, syy = 0.f, szz = 0.f;
  float mnx = 1e30f, mny = 1e30f, mnz = 1e30f, mxx = -1e30f, mxy = -1e30f, mxz = -1e30f;
  for (int e = e0 + sub; e < e1; e += 4) {
    int s = s_idx[e];
    float rx = spos[s * 3 + 0] - qx;
    float ry = spos[s * 3 + 1] - qy;
    float rz = spos[s * 3 + 2] - qz;
    cnt += 1.f;
    sx += rx; sy += ry; sz += rz;
    sxx += rx * rx; syy += ry * ry; szz += rz * rz;
    mnx = fminf(mnx, rx); mny = fminf(mny, ry); mnz = fminf(mnz, rz);
    mxx = fmaxf(mxx, rx); mxy = fmaxf(mxy, ry); mxz = fmaxf(mxz, rz);
  }
#pragma unroll
  for (int msk = 1; msk <= 2; msk <<= 1) {
    cnt += __shfl_xor(cnt, msk);
    sx += __shfl_xor(sx, msk); sy += __shfl_xor(sy, msk); sz += __shfl_xor(sz, msk);
    sxx += __shfl_xor(sxx, msk); syy += __shfl_xor(syy, msk); szz += __shfl_xor(szz, msk);
    mnx = fminf(mnx, __shfl_xor(mnx, msk));
    mny = fminf(mny, __shfl_xor(mny, msk));
    mnz = fminf(mnz, __shfl_xor(mnz, msk));
    mxx = fmaxf(mxx, __shfl_xor(mxx, msk));
    mxy = fmaxf(mxy, __shfl_xor(mxy, msk));
    mxz = fmaxf(mxz, __shfl_xor(mxz, msk));
  }
  if (sub == 0) {
    float c = fmaxf(cnt, 1.f);
    float mx_ = sx / c, my_ = sy / c, mz_ = sz / c;
    float vx = fmaxf(sxx / c - mx_ * mx_, 0.f);
    float vy = fmaxf(syy / c - my_ * my_, 0.f);
    float vz = fmaxf(szz / c - mz_ * mz_, 0.f);
    float* r = raw + (size_t)q * 12;
    r[0] = mx_; r[1] = my_; r[2] = mz_;
    r[3] = sqrtf(vx); r[4] = sqrtf(vy); r[5] = sqrtf(vz);
    r[6] = fminf(fmaxf(mnx, -100.f), 100.f);
    r[7] = fminf(fmaxf(mny, -100.f), 100.f);
    r[8] = fminf(fmaxf(mnz, -100.f), 100.f);
    r[9] = fminf(fmaxf(mxx, -100.f), 100.f);
    r[10] = fminf(fmaxf(mxy, -100.f), 100.f);
    r[11] = fminf(fmaxf(mxz, -100.f), 100.f);
  }
}

// ---------------- geo MLP: raw [Q,12] -> geo bf16 [Q,128] ----------------
__global__ __launch_bounds__(128) void geo_mlp_kernel(
    const float* raw, const float* Gw1, const float* Gb1,
    const float* Gw2, const float* Gb2, unsigned short* geo_b) {
  int qb = blockIdx.x * 8;
  int j = threadIdx.x;
  __shared__ float rs[8][12];
  __shared__ float h1[8][128];
  if (j < 96) rs[j / 12][j % 12] = raw[(size_t)(qb + j / 12) * 12 + (j % 12)];
  __syncthreads();
  float b1 = Gb1[j];
  float acc[8];
#pragma unroll
  for (int qq = 0; qq < 8; ++qq) acc[qq] = b1;
  for (int i = 0; i < 12; ++i) {
    float w = Gw1[i * GEON + j];
#pragma unroll
    for (int qq = 0; qq < 8; ++qq) acc[qq] += rs[qq][i] * w;
  }
#pragma unroll
  for (int qq = 0; qq < 8; ++qq) h1[qq][j] = gelu_f(acc[qq]);
  __syncthreads();
  float b2 = Gb2[j];
  float acc2[8];
#pragma unroll
  for (int qq = 0; qq < 8; ++qq) acc2[qq] = b2;
  for (int k = 0; k < 128; ++k) {
    float w = Gw2[k * GEON + j];
#pragma unroll
    for (int qq = 0; qq < 8; ++qq) acc2[qq] += h1[qq][k] * w;
  }
#pragma unroll
  for (int qq = 0; qq < 8; ++qq)
    geo_b[(size_t)(qb + qq) * GEON + j] = f2b(gelu_f(acc2[qq]));
}

// ---------------- specialized KV GEMM with B register-prefetch ----------------
// KV[32768,512] = bf16( fp32 A[32768,256] @ B ), BT bf16 [512,256].
// A staged ONCE (fp32->bf16, 32KB); B in 16 col-tiles of 32 (16KB), the NEXT
// tile's global loads are issued into registers right after the barrier so the
// MFMA+epilogue hides their latency (drained by the loop-end barrier's vmcnt).
__global__ __launch_bounds__(256) void kv_gemm(
    const float* A, const unsigned short* BT, unsigned short* KVb) {
  __shared__ unsigned short As[64 * 256];   // 32 KB
  __shared__ unsigned short Bs[32 * 256];   // 16 KB
  int t = threadIdx.x;
  int bm = blockIdx.x * 64;
  int w = t >> 6, lane = t & 63;
  int quad = lane >> 4, l16 = lane & 15;
  int wr = w >> 1, wc = w & 1;
  int srow = t >> 2, sub = t & 3;
  // stage A tile once: 64 rows x 256 K, fp32 -> bf16
  {
    const float* Ag = A + (size_t)(bm + srow) * 256 + sub * 64;
#pragma unroll
    for (int i = 0; i < 8; ++i) {
      float4 f0 = *(const float4*)(Ag + i * 8);
      float4 f1 = *(const float4*)(Ag + i * 8 + 4);
      u16x8 u;
      u[0] = f2b(f0.x); u[1] = f2b(f0.y); u[2] = f2b(f0.z); u[3] = f2b(f0.w);
      u[4] = f2b(f1.x); u[5] = f2b(f1.y); u[6] = f2b(f1.z); u[7] = f2b(f1.w);
      *lds_gk<256>(As, srow, sub * 64 + i * 8) = u;
    }
  }
  int brow = t >> 3, bsub = t & 7;  // 32 rows x 8 chunks of 32 for B staging
  u16x8 pre[4];
  {
    const unsigned short* Bg = BT + (size_t)brow * 256 + bsub * 32;
#pragma unroll
    for (int i = 0; i < 4; ++i) pre[i] = *reinterpret_cast<const u16x8*>(Bg + i * 8);
  }
  for (int ct = 0; ct < 16; ++ct) {
#pragma unroll
    for (int i = 0; i < 4; ++i)
      *lds_gk<256>(Bs, brow, bsub * 32 + i * 8) = pre[i];
    __syncthreads();
    if (ct < 15) {  // issue next tile's loads now; latency hidden under MFMA
      const unsigned short* Bg = BT + (size_t)((ct + 1) * 32 + brow) * 256 + bsub * 32;
#pragma unroll
      for (int i = 0; i < 4; ++i) pre[i] = *reinterpret_cast<const u16x8*>(Bg + i * 8);
    }
    f32x4 acc[2];
    acc[0] = (f32x4){0.f, 0.f, 0.f, 0.f};
    acc[1] = (f32x4){0.f, 0.f, 0.f, 0.f};
#pragma unroll
    for (int k = 0; k < 8; ++k) {
      bf16x8 a0 = *reinterpret_cast<bf16x8*>(lds_gk<256>(As, wr * 32 + l16, k * 32 + quad * 8));
      bf16x8 a1 = *reinterpret_cast<bf16x8*>(lds_gk<256>(As, wr * 32 + 16 + l16, k * 32 + quad * 8));
      bf16x8 b0 = *reinterpret_cast<bf16x8*>(lds_gk<256>(Bs, wc * 16 + l16, k * 32 + quad * 8));
      acc[0] = __builtin_amdgcn_mfma_f32_16x16x32_bf16(a0, b0, acc[0], 0, 0, 0);
      acc[1] = __builtin_amdgcn_mfma_f32_16x16x32_bf16(a1, b0, acc[1], 0, 0, 0);
    }
#pragma unroll
    for (int i = 0; i < 2; ++i)
#pragma unroll
      for (int r = 0; r < 4; ++r) {
        int rw = bm + wr * 32 + i * 16 + quad * 4 + r;
        int col = ct * 32 + wc * 16 + l16;
        KVb[(size_t)rw * 512 + col] = f2b(acc[i][r]);
      }
    __syncthreads();  // protect Bs before next restage
  }
}

// ---------------- panel-resident single-barrier GEMM, 64x64 tile ----------------
// Stage full A-panel [64xKT] + B-panel [64xKT] (XOR-swizzled), ONE barrier,
// then uninterrupted KT/32-step MFMA loop. AMODE: 0 = A bf16, 1 = A fp32 with
// fused LayerNorm (row stats via 4-lane shuffle during staging).
template <int KT, int AMODE, bool HAS_BIAS, bool DO_GELU, bool HAS_RESID, bool STORE_F32>
__global__ __launch_bounds__(256) void gemm_panel(
    const void* Ap, const unsigned short* BT, int N,
    const float* lng, const float* lnb,
    const float* bias, const float* resid, float* outF, unsigned short* outB) {
  __shared__ unsigned short As[64 * KT];
  __shared__ unsigned short Bs[64 * KT];
  int t = threadIdx.x;
  int bm = blockIdx.x * 64, bn = blockIdx.y * 64;
  int row = t >> 2, sub = t & 3;     // 4 threads per panel row
  constexpr int CH = KT / 4;         // elems per thread per row

  // ---- stage A ----
  if constexpr (AMODE == 1) {
    static_assert(KT == 256, "LN fusion assumes D=256 rows");
    const float* Ag = (const float*)Ap + (size_t)(bm + row) * 256 + sub * 64;
    float va[64];
    float s = 0.f, ss = 0.f;
#pragma unroll
    for (int i = 0; i < 16; ++i) {
      float4 v = *(const float4*)(Ag + i * 4);
      va[i * 4 + 0] = v.x; va[i * 4 + 1] = v.y;
      va[i * 4 + 2] = v.z; va[i * 4 + 3] = v.w;
      s += v.x + v.y + v.z + v.w;
      ss += v.x * v.x + v.y * v.y + v.z * v.z + v.w * v.w;
    }
    s += __shfl_xor(s, 1);  s += __shfl_xor(s, 2);     // 4 lanes of one row
    ss += __shfl_xor(ss, 1); ss += __shfl_xor(ss, 2);
    float mean = s * (1.f / 256.f);
    float var = ss * (1.f / 256.f) - mean * mean;
    float rstd = 1.0f / sqrtf(var + 1e-5f);
#pragma unroll
    for (int i = 0; i < 8; ++i) {
      int c0 = sub * 64 + i * 8;
      float4 g0 = *(const float4*)(lng + c0);
      float4 g1 = *(const float4*)(lng + c0 + 4);
      float4 b0 = *(const float4*)(lnb + c0);
      float4 b1 = *(const float4*)(lnb + c0 + 4);
      u16x8 u;
      u[0] = f2b((va[i * 8 + 0] - mean) * rstd * g0.x + b0.x);
      u[1] = f2b((va[i * 8 + 1] - mean) * rstd * g0.y + b0.y);
      u[2] = f2b((va[i * 8 + 2] - mean) * rstd * g0.z + b0.z);
      u[3] = f2b((va[i * 8 + 3] - mean) * rstd * g0.w + b0.w);
      u[4] = f2b((va[i * 8 + 4] - mean) * rstd * g1.x + b1.x);
      u[5] = f2b((va[i * 8 + 5] - mean) * rstd * g1.y + b1.y);
      u[6] = f2b((va[i * 8 + 6] - mean) * rstd * g1.z + b1.z);
      u[7] = f2b((va[i * 8 + 7] - mean) * rstd * g1.w + b1.w);
      *lds_gk<256>(As, row, c0) = u;
    }
  } else {
    const unsigned short* Ag = (const unsigned short*)Ap + (size_t)(bm + row) * KT + sub * CH;
#pragma unroll
    for (int i = 0; i < CH / 8; ++i)
      *lds_gk<KT>(As, row, sub * CH + i * 8) = *reinterpret_cast<const u16x8*>(Ag + i * 8);
  }
  // ---- stage B ----
  {
    const unsigned short* Bg = BT + (size_t)(bn + row) * KT + sub * CH;
#pragma unroll
    for (int i = 0; i < CH / 8; ++i)
      *lds_gk<KT>(Bs, row, sub * CH + i * 8) = *reinterpret_cast<const u16x8*>(Bg + i * 8);
  }
  __syncthreads();

  // ---- MFMA loop, no further barriers ----
  int w = t >> 6, lane = t & 63;
  int wr = w >> 1, wc = w & 1;
  int quad = lane >> 4, l16 = lane & 15;
  f32x4 acc[2][2];
#pragma unroll
  for (int i = 0; i < 2; ++i)
#pragma unroll
    for (int j = 0; j < 2; ++j) acc[i][j] = (f32x4){0.f, 0.f, 0.f, 0.f};
#pragma unroll
  for (int k = 0; k < KT / 32; ++k) {
    bf16x8 a0 = *reinterpret_cast<bf16x8*>(lds_gk<KT>(As, wr * 32 + l16, k * 32 + quad * 8));
    bf16x8 a1 = *reinterpret_cast<bf16x8*>(lds_gk<KT>(As, wr * 32 + 16 + l16, k * 32 + quad * 8));
    bf16x8 b0 = *reinterpret_cast<bf16x8*>(lds_gk<KT>(Bs, wc * 32 + l16, k * 32 + quad * 8));
    bf16x8 b1 = *reinterpret_cast<bf16x8*>(lds_gk<KT>(Bs, wc * 32 + 16 + l16, k * 32 + quad * 8));
    acc[0][0] = __builtin_amdgcn_mfma_f32_16x16x32_bf16(a0, b0, acc[0][0], 0, 0, 0);
    acc[0][1] = __builtin_amdgcn_mfma_f32_16x16x32_bf16(a0, b1, acc[0][1], 0, 0, 0);
    acc[1][0] = __builtin_amdgcn_mfma_f32_16x16x32_bf16(a1, b0, acc[1][0], 0, 0, 0);
    acc[1][1] = __builtin_amdgcn_mfma_f32_16x16x32_bf16(a1, b1, acc[1][1], 0, 0, 0);
  }

  // ---- epilogue ----
#pragma unroll
  for (int i = 0; i < 2; ++i)
#pragma unroll
    for (int j = 0; j < 2; ++j) {
      int col = bn + wc * 32 + j * 16 + l16;
      float bv = HAS_BIAS ? bias[col] : 0.f;
#pragma unroll
      for (int r = 0; r < 4; ++r) {
        int rw = bm + wr * 32 + i * 16 + quad * 4 + r;
        float v = acc[i][j][r] + bv;
        if (DO_GELU) v = gelu_f(v);
        if (HAS_RESID) v += resid[(size_t)rw * N + col];
        if (STORE_F32) outF[(size_t)rw * N + col] = v;
        else outB[(size_t)rw * N + col] = f2b(v);
      }
    }
}

// ---------------- generic bf16 MFMA GEMM (kept for FFN2, K=512) ----------------
template <bool A_FP32, bool COLGRID, bool HAS_BIAS, bool DO_GELU, bool HAS_RESID, bool STORE_F32>
__global__ __launch_bounds__(256) void gemm64(
    const void* Ap, const unsigned short* BT, int M, int N, int K,
    const float* bias, const float* resid, float* outF, unsigned short* outB) {
  __shared__ unsigned short As[64][40];
  __shared__ unsigned short Bs[64][40];
  int t = threadIdx.x;
  int bm = (COLGRID ? blockIdx.x : blockIdx.y) * 64;
  int bn = (COLGRID ? blockIdx.y : blockIdx.x) * 64;
  int w = t >> 6, lane = t & 63;
  int wr = w >> 1, wc = w & 1;
  int quad = lane >> 4, l16 = lane & 15;
  int row = t >> 2, chunk = t & 3;

  f32x4 acc[2][2];
#pragma unroll
  for (int i = 0; i < 2; ++i)
#pragma unroll
    for (int j = 0; j < 2; ++j) acc[i][j] = (f32x4){0.f, 0.f, 0.f, 0.f};

  for (int k0 = 0; k0 < K; k0 += 32) {
    if (A_FP32) {
      const float* Ag = (const float*)Ap + (size_t)(bm + row) * K + k0 + chunk * 8;
      float4 f0 = *(const float4*)Ag;
      float4 f1 = *(const float4*)(Ag + 4);
      u16x8 u;
      u[0] = f2b(f0.x); u[1] = f2b(f0.y); u[2] = f2b(f0.z); u[3] = f2b(f0.w);
      u[4] = f2b(f1.x); u[5] = f2b(f1.y); u[6] = f2b(f1.z); u[7] = f2b(f1.w);
      *reinterpret_cast<u16x8*>(&As[row][chunk * 8]) = u;
    } else {
      const unsigned short* Ag = (const unsigned short*)Ap + (size_t)(bm + row) * K + k0 + chunk * 8;
      *reinterpret_cast<u16x8*>(&As[row][chunk * 8]) = *reinterpret_cast<const u16x8*>(Ag);
    }
    {
      const unsigned short* Bg = BT + (size_t)(bn + row) * K + k0 + chunk * 8;
      *reinterpret_cast<u16x8*>(&Bs[row][chunk * 8]) = *reinterpret_cast<const u16x8*>(Bg);
    }
    __syncthreads();
    bf16x8 a0 = *reinterpret_cast<const bf16x8*>(&As[wr * 32 + l16][quad * 8]);
    bf16x8 a1 = *reinterpret_cast<const bf16x8*>(&As[wr * 32 + 16 + l16][quad * 8]);
    bf16x8 b0 = *reinterpret_cast<const bf16x8*>(&Bs[wc * 32 + l16][quad * 8]);
    bf16x8 b1 = *reinterpret_cast<const bf16x8*>(&Bs[wc * 32 + 16 + l16][quad * 8]);
    acc[0][0] = __builtin_amdgcn_mfma_f32_16x16x32_bf16(a0, b0, acc[0][0], 0, 0, 0);
    acc[0][1] = __builtin_amdgcn_mfma_f32_16x16x32_bf16(a0, b1, acc[0][1], 0, 0, 0);
    acc[1][0] = __builtin_amdgcn_mfma_f32_16x16x32_bf16(a1, b0, acc[1][0], 0, 0, 0);
    acc[1][1] = __builtin_amdgcn_mfma_f32_16x16x32_bf16(a1, b1, acc[1][1], 0, 0, 0);
    __syncthreads();
  }

#pragma unroll
  for (int i = 0; i < 2; ++i)
#pragma unroll
    for (int j = 0; j < 2; ++j) {
      int col = bn + wc * 32 + j * 16 + l16;
      float bv = HAS_BIAS ? bias[col] : 0.f;
#pragma unroll
      for (int r = 0; r < 4; ++r) {
        int rw = bm + wr * 32 + i * 16 + quad * 4 + r;
        float v = acc[i][j][r] + bv;
        if (DO_GELU) v = gelu_f(v);
        if (HAS_RESID) v += resid[(size_t)rw * N + col];
        if (STORE_F32) outF[(size_t)rw * N + col] = v;
        else outB[(size_t)rw * N + col] = f2b(v);
      }
    }
}

// ---------------- edge attention: one wave/query, 2 edges per iteration ----------------
// g is pulled OUT of the online-softmax loop: sum_e alpha*(v+g) =
// sum_e alpha*v + g * sum_e alpha, with sum(alpha) = l*em/denom (exact, handles
// empty segments and the 1e-8 clamp). Shortens the dependent chain by 8 FMA/iter.
__global__ __launch_bounds__(256) void attn_edge_kernel(
    const unsigned short* Qb, const unsigned short* Gfb, const unsigned short* KVb,
    const int* s_idx, const int* offs, const float* log_tau, unsigned short* attn_b) {
  int q = blockIdx.x * 4 + (threadIdx.x >> 6);
  int lane = threadIdx.x & 63;
  int half = lane >> 5;
  int sl = lane & 31;
  int d0 = sl * 8;
  int e0 = offs[q], e1 = offs[q + 1];
  float invs = expf(-log_tau[0]) * 0.17677669529663687f;  // 1/(sqrt(32)*tau)
  u16x8 qu = *(const u16x8*)(Qb + (size_t)q * DN + d0);
  u16x8 gu = *(const u16x8*)(Gfb + (size_t)q * DN + d0);
  float qf[8], gf[8];
#pragma unroll
  for (int j = 0; j < 8; ++j) { qf[j] = b2f(qu[j]) * invs; gf[j] = b2f(gu[j]); }
  const float NEG = -1e30f;
  float m = -INFINITY, l = 0.f;
  float a[8];
#pragma unroll
  for (int j = 0; j < 8; ++j) a[j] = 0.f;
  for (int e = e0; e < e1; e += 2) {
    int ee = e + half;
    bool valid = ee < e1;
    int s = s_idx[valid ? ee : (e1 - 1)];
    const unsigned short* kr = KVb + (size_t)s * 512 + d0;
    u16x8 ku = *(const u16x8*)kr;
    u16x8 vu = *(const u16x8*)(kr + 256);
    float p = 0.f;
#pragma unroll
    for (int j = 0; j < 8; ++j) p += qf[j] * b2f(ku[j]);
    p += __shfl_xor(p, 1);
    p += __shfl_xor(p, 2);       // per-head score across the head's 4 lanes
    if (!valid) p = -INFINITY;
    float mnew = fmaxf(m, p);
    float sc = (m > NEG) ? __expf(m - mnew) : 0.f;
    float we = valid ? __expf(p - mnew) : 0.f;
    l = l * sc + we;
#pragma unroll
    for (int j = 0; j < 8; ++j) a[j] = a[j] * sc + we * b2f(vu[j]);
    m = mnew;
  }
  // merge the two half-wave states
  float om = __shfl_xor(m, 32);
  float ol = __shfl_xor(l, 32);
  float M2 = fmaxf(m, om);
  float ws = (m > NEG) ? __expf(m - M2) : 0.f;
  float wo = (om > NEG) ? __expf(om - M2) : 0.f;
  l = l * ws + ol * wo;
#pragma unroll
  for (int j = 0; j < 8; ++j) {
    float oa = __shfl_xor(a[j], 32);
    a[j] = a[j] * ws + oa * wo;
  }
  // reference: M = max(0, seg_max); denom = max(sum exp(s-M), 1e-8)
  float M = fmaxf(M2, 0.f);
  float em = (M2 > NEG) ? __expf(M2 - M) : 0.f;
  float denom = fmaxf(l * em, 1e-8f);
  float f = em / denom;
  float sa = l * f;              // = sum(alpha)
  if (half == 0) {
    u16x8 o;
#pragma unroll
    for (int j = 0; j < 8; ++j) o[j] = f2b(a[j] * f + gf[j] * sa);
    *(u16x8*)(attn_b + (size_t)q * DN + d0) = o;
  }
}

extern "C" void kernel_launch(void* const* d_in, const int* in_sizes, int n_in,
                              void* d_out, int out_size, void* d_ws, size_t ws_size,
                              hipStream_t stream) {
  const float* query_tokens  = (const float*)d_in[0];
  const float* query_pos     = (const float*)d_in[1];
  const float* support_feats = (const float*)d_in[2];
  const float* support_pos   = (const float*)d_in[3];
  const float* Wq  = (const float*)d_in[4];
  const float* Wk  = (const float*)d_in[5];
  const float* Wv  = (const float*)d_in[6];
  const float* Wg  = (const float*)d_in[7];
  const float* Wo  = (const float*)d_in[8];
  const float* bo  = (const float*)d_in[9];
  const float* log_tau = (const float*)d_in[10];
  const float* ln1_g = (const float*)d_in[11];
  const float* ln1_b = (const float*)d_in[12];
  const float* ln2_g = (const float*)d_in[13];
  const float* ln2_b = (const float*)d_in[14];
  const float* Wf1 = (const float*)d_in[15];
  const float* bf1 = (const float*)d_in[16];
  const float* Wf2 = (const float*)d_in[17];
  const float* bf2 = (const float*)d_in[18];
  const float* Gw1 = (const float*)d_in[19];
  const float* Gb1 = (const float*)d_in[20];
  const float* Gw2 = (const float*)d_in[21];
  const float* Gb2 = (const float*)d_in[22];
  const int* q_idx = (const int*)d_in[23];
  const int* s_idx = (const int*)d_in[24];
  float* out = (float*)d_out;

  char* ws = (char*)d_ws;
  size_t off = 0;
  auto alloc = [&](size_t bytes) -> void* {
    void* p = ws + off;
    off = (off + bytes + 255) & ~(size_t)255;
    return p;
  };
  unsigned short* WqT  = (unsigned short*)alloc(65536 * 2);
  unsigned short* WkvT = (unsigned short*)alloc(131072 * 2);
  unsigned short* WgT  = (unsigned short*)alloc(32768 * 2);
  unsigned short* WoT  = (unsigned short*)alloc(65536 * 2);
  unsigned short* Wf1T = (unsigned short*)alloc(131072 * 2);
  unsigned short* Wf2T = (unsigned short*)alloc(131072 * 2);
  int* offs            = (int*)alloc((QN + 1) * 4);
  float* raw           = (float*)alloc((size_t)QN * 12 * 4);
  unsigned short* geo_b = (unsigned short*)alloc((size_t)QN * GEON * 2);
  unsigned short* Qb    = (unsigned short*)alloc((size_t)QN * DN * 2);
  unsigned short* Gf_b  = (unsigned short*)alloc((size_t)QN * DN * 2);
  unsigned short* KVb   = (unsigned short*)alloc((size_t)SN * 512 * 2);
  unsigned short* attn_b = (unsigned short*)alloc((size_t)QN * DN * 2);
  float* x1             = (float*)alloc((size_t)QN * DN * 4);
  unsigned short* h_b   = (unsigned short*)alloc((size_t)QN * FFNN * 2);

  // 1. weight prep (bf16 transposed copies)
  transpose_weights<<<136, 256, 0, stream>>>(Wq, Wk, Wv, Wg, Wo, Wf1, Wf2,
                                             WqT, WkvT, WgT, WoT, Wf1T, Wf2T);
  // 2. segment offsets
  seg_offsets<<<33, 256, 0, stream>>>(q_idx, offs);
  // 3. geo stats
  geo_stats_kernel<<<QN / 64, 256, 0, stream>>>(query_pos, support_pos, offs, s_idx, raw);
  // 4. geo MLP
  geo_mlp_kernel<<<QN / 8, 128, 0, stream>>>(raw, Gw1, Gb1, Gw2, Gb2, geo_b);
  // 5. KV = support_feats @ [Wk|Wv]
  kv_gemm<<<SN / 64, 256, 0, stream>>>(support_feats, WkvT, KVb);
  // 6. Qf = LN1(query_tokens) @ Wq  (LN fused into A staging)
  gemm_panel<256, 1, false, false, false, false><<<dim3(QN / 64, 4), 256, 0, stream>>>(
      query_tokens, WqT, DN, ln1_g, ln1_b, nullptr, nullptr, nullptr, Qb);
  // 7. Gf = geo @ Wg
  gemm_panel<128, 0, false, false, false, false><<<dim3(QN / 64, 4), 256, 0, stream>>>(
      geo_b, WgT, DN, nullptr, nullptr, nullptr, nullptr, nullptr, Gf_b);
  // 8. edge attention -> attn_b bf16
  attn_edge_kernel<<<QN / 4, 256, 0, stream>>>(Qb, Gf_b, KVb, s_idx, offs, log_tau, attn_b);
  // 9. x1 = attn @ Wo + bo + query_tokens, store fp32
  gemm_panel<256, 0, true, false, true, true><<<dim3(QN / 64, 4), 256, 0, stream>>>(
      attn_b, WoT, DN, nullptr, nullptr, bo, query_tokens, x1, nullptr);
  // 10. h = gelu(LN2(x1) @ Wf1 + bf1)  (LN fused into A staging)
  gemm_panel<256, 1, true, true, false, false><<<dim3(QN / 64, 8), 256, 0, stream>>>(
      x1, Wf1T, FFNN, ln2_g, ln2_b, bf1, nullptr, nullptr, h_b);
  // 11. out = h @ Wf2 + bf2 + x1, store fp32 -> d_out
  gemm64<false, true, true, false, true, true><<<dim3(QN / 64, DN / 64), 256, 0, stream>>>(
      h_b, Wf2T, QN, DN, 512, bf2, x1, out, nullptr);

  (void)in_sizes; (void)n_in; (void)out_size; (void)ws_size;
}

// Round 3
// 247.824 us; speedup vs baseline: 1.1138x; 1.1138x over previous
//
#include <hip/hip_runtime.h>
#include <math.h>

#define QN 8192
#define SN 32768
#define EN 131072
#define DN 256
#define HN 8
#define HDN 32
#define GEON 128
#define FFNN 512

typedef __attribute__((ext_vector_type(8))) short bf16x8;
typedef __attribute__((ext_vector_type(8))) unsigned short u16x8;
typedef __attribute__((ext_vector_type(4))) unsigned short u16x4;
typedef __attribute__((ext_vector_type(4))) float f32x4;

__device__ __forceinline__ unsigned short f2b(float f) {
  union { float f; unsigned u; } v; v.f = f;
  unsigned u = v.u;
  u += 0x7fffu + ((u >> 16) & 1u);   // round-to-nearest-even
  return (unsigned short)(u >> 16);
}
__device__ __forceinline__ float b2f(unsigned short h) {
  union { unsigned u; float f; } v; v.u = ((unsigned)h) << 16; return v.f;
}
__device__ __forceinline__ float gelu_f(float x) {
  return 0.5f * x * (1.0f + erff(x * 0.70710678118654752440f));
}

// XOR swizzle in 8-element groups: phys_g = g ^ (row&7). Staging writes and
// fragment reads both land at the b128 minimum aliasing (conflict-free).
template <int KT>
__device__ __forceinline__ u16x8* lds_gk(unsigned short* base, int row, int col) {
  int g = (col >> 3) ^ (row & 7);
  return reinterpret_cast<u16x8*>(base + row * KT + g * 8);
}

// ---------------- tiled transpose: fp32 [K,N] -> bf16 [N,K] ----------------
__global__ __launch_bounds__(256) void transpose_weights(
    const float* Wq, const float* Wk, const float* Wv, const float* Wg,
    const float* Wo, const float* Wf1, const float* Wf2,
    unsigned short* WqT, unsigned short* WkvT, unsigned short* WgT,
    unsigned short* WoT, unsigned short* Wf1T, unsigned short* Wf2T) {
  int b = blockIdx.x;
  const float* src; unsigned short* dst; int K, N, tile;
  if (b < 16)       { src = Wq;  dst = WqT;          K = 256; N = 256; tile = b; }
  else if (b < 32)  { src = Wk;  dst = WkvT;         K = 256; N = 256; tile = b - 16; }
  else if (b < 48)  { src = Wv;  dst = WkvT + 65536; K = 256; N = 256; tile = b - 32; }
  else if (b < 56)  { src = Wg;  dst = WgT;          K = 128; N = 256; tile = b - 48; }
  else if (b < 72)  { src = Wo;  dst = WoT;          K = 256; N = 256; tile = b - 56; }
  else if (b < 104) { src = Wf1; dst = Wf1T;         K = 256; N = 512; tile = b - 72; }
  else              { src = Wf2; dst = Wf2T;         K = 512; N = 256; tile = b - 104; }
  int ktiles = K >> 6;
  int k0 = (tile % ktiles) * 64, n0 = (tile / ktiles) * 64;
  __shared__ float ts[64][65];
  int t = threadIdx.x;
  int c4 = (t & 15) * 4;
  int r = t >> 4;
#pragma unroll
  for (int p = 0; p < 4; ++p) {
    int row = p * 16 + r;
    float4 v = *(const float4*)(src + (size_t)(k0 + row) * N + n0 + c4);
    ts[row][c4 + 0] = v.x; ts[row][c4 + 1] = v.y;
    ts[row][c4 + 2] = v.z; ts[row][c4 + 3] = v.w;
  }
  __syncthreads();
#pragma unroll
  for (int p = 0; p < 4; ++p) {
    int n = p * 16 + r;
    ushort4 o;
    o.x = f2b(ts[c4 + 0][n]); o.y = f2b(ts[c4 + 1][n]);
    o.z = f2b(ts[c4 + 2][n]); o.w = f2b(ts[c4 + 3][n]);
    *(ushort4*)(dst + (size_t)(n0 + n) * K + k0 + c4) = o;
  }
}

// ---------------- segment offsets from sorted q_idx ----------------
__global__ __launch_bounds__(256) void seg_offsets(const int* q_idx, int* offs) {
  int i = blockIdx.x * 256 + threadIdx.x;
  if (i > QN) return;
  int lo = 0, hi = EN;
  while (lo < hi) {
    int mid = (lo + hi) >> 1;
    if (q_idx[mid] < i) lo = mid + 1; else hi = mid;
  }
  offs[i] = lo;
}

// ---------------- per-query geo stats -> raw [Q,12] ----------------
__global__ __launch_bounds__(256) void geo_stats_kernel(
    const float* qpos, const float* spos, const int* offs, const int* s_idx, float* raw) {
  int q = blockIdx.x * 64 + (threadIdx.x >> 2);
  int sub = threadIdx.x & 3;
  int e0 = offs[q], e1 = offs[q + 1];
  float qx = qpos[q * 3 + 0], qy = qpos[q * 3 + 1], qz = qpos[q * 3 + 2];
  float cnt = 0.f, sx = 0.f, sy = 0.f, sz = 0.f, sxx = 0.f, syy = 0.f, szz = 0.f;
  float mnx = 1e30f, mny = 1e30f, mnz = 1e30f, mxx = -1e30f, mxy = -1e30f, mxz = -1e30f;
  for (int e = e0 + sub; e < e1; e += 4) {
    int s = s_idx[e];
    float rx = spos[s * 3 + 0] - qx;
    float ry = spos[s * 3 + 1] - qy;
    float rz = spos[s * 3 + 2] - qz;
    cnt += 1.f;
    sx += rx; sy += ry; sz += rz;
    sxx += rx * rx; syy += ry * ry; szz += rz * rz;
    mnx = fminf(mnx, rx); mny = fminf(mny, ry); mnz = fminf(mnz, rz);
    mxx = fmaxf(mxx, rx); mxy = fmaxf(mxy, ry); mxz = fmaxf(mxz, rz);
  }
#pragma unroll
  for (int msk = 1; msk <= 2; msk <<= 1) {
    cnt += __shfl_xor(cnt, msk);
    sx += __shfl_xor(sx, msk); sy += __shfl_xor(sy, msk); sz += __shfl_xor(sz, msk);
    sxx += __shfl_xor(sxx, msk); syy += __shfl_xor(syy, msk); szz += __shfl_xor(szz, msk);
    mnx = fminf(mnx, __shfl_xor(mnx, msk));
    mny = fminf(mny, __shfl_xor(mny, msk));
    mnz = fminf(mnz, __shfl_xor(mnz, msk));
    mxx = fmaxf(mxx, __shfl_xor(mxx, msk));
    mxy = fmaxf(mxy, __shfl_xor(mxy, msk));
    mxz = fmaxf(mxz, __shfl_xor(mxz, msk));
  }
  if (sub == 0) {
    float c = fmaxf(cnt, 1.f);
    float mx_ = sx / c, my_ = sy / c, mz_ = sz / c;
    float vx = fmaxf(sxx / c - mx_ * mx_, 0.f);
    float vy = fmaxf(syy / c - my_ * my_, 0.f);
    float vz = fmaxf(szz / c - mz_ * mz_, 0.f);
    float* r = raw + (size_t)q * 12;
    r[0] = mx_; r[1] = my_; r[2] = mz_;
    r[3] = sqrtf(vx); r[4] = sqrtf(vy); r[5] = sqrtf(vz);
    r[6] = fminf(fmaxf(mnx, -100.f), 100.f);
    r[7] = fminf(fmaxf(mny, -100.f), 100.f);
    r[8] = fminf(fmaxf(mnz, -100.f), 100.f);
    r[9] = fminf(fmaxf(mxx, -100.f), 100.f);
    r[10] = fminf(fmaxf(mxy, -100.f), 100.f);
    r[11] = fminf(fmaxf(mxz, -100.f), 100.f);
  }
}

// ---------------- geo MLP: raw [Q,12] -> geo bf16 [Q,128] ----------------
__global__ __launch_bounds__(128) void geo_mlp_kernel(
    const float* raw, const float* Gw1, const float* Gb1,
    const float* Gw2, const float* Gb2, unsigned short* geo_b) {
  int qb = blockIdx.x * 8;
  int j = threadIdx.x;
  __shared__ float rs[8][12];
  __shared__ float h1[8][128];
  if (j < 96) rs[j / 12][j % 12] = raw[(size_t)(qb + j / 12) * 12 + (j % 12)];
  __syncthreads();
  float b1 = Gb1[j];
  float acc[8];
#pragma unroll
  for (int qq = 0; qq < 8; ++qq) acc[qq] = b1;
  for (int i = 0; i < 12; ++i) {
    float w = Gw1[i * GEON + j];
#pragma unroll
    for (int qq = 0; qq < 8; ++qq) acc[qq] += rs[qq][i] * w;
  }
#pragma unroll
  for (int qq = 0; qq < 8; ++qq) h1[qq][j] = gelu_f(acc[qq]);
  __syncthreads();
  float b2 = Gb2[j];
  float acc2[8];
#pragma unroll
  for (int qq = 0; qq < 8; ++qq) acc2[qq] = b2;
  for (int k = 0; k < 128; ++k) {
    float w = Gw2[k * GEON + j];
#pragma unroll
    for (int qq = 0; qq < 8; ++qq) acc2[qq] += h1[qq][k] * w;
  }
#pragma unroll
  for (int qq = 0; qq < 8; ++qq)
    geo_b[(size_t)(qb + qq) * GEON + j] = f2b(gelu_f(acc2[qq]));
}

// ---------------- layernorm fp32 [Q,256] -> bf16, one wave per row ----------------
__global__ __launch_bounds__(256) void ln_kernel(
    const float* x, const float* g, const float* b, unsigned short* out) {
  int row = blockIdx.x * 4 + (threadIdx.x >> 6);
  int lane = threadIdx.x & 63;
  const float* xr = x + (size_t)row * DN;
  float4 v = *(const float4*)(xr + lane * 4);
  float s = v.x + v.y + v.z + v.w;
  float ss = v.x * v.x + v.y * v.y + v.z * v.z + v.w * v.w;
#pragma unroll
  for (int msk = 1; msk <= 32; msk <<= 1) {
    s += __shfl_xor(s, msk);
    ss += __shfl_xor(ss, msk);
  }
  float mean = s * (1.f / 256.f);
  float var = ss * (1.f / 256.f) - mean * mean;
  float rs = 1.0f / sqrtf(var + 1e-5f);
  float4 gg = *(const float4*)(g + lane * 4);
  float4 bb = *(const float4*)(b + lane * 4);
  unsigned short* o = out + (size_t)row * DN + lane * 4;
  o[0] = f2b((v.x - mean) * rs * gg.x + bb.x);
  o[1] = f2b((v.y - mean) * rs * gg.y + bb.y);
  o[2] = f2b((v.z - mean) * rs * gg.z + bb.z);
  o[3] = f2b((v.w - mean) * rs * gg.w + bb.w);
}

// ---------------- specialized KV GEMM with B register-prefetch ----------------
// KV[32768,512] = bf16( fp32 A[32768,256] @ B ), BT bf16 [512,256].
// A staged ONCE (fp32->bf16, 32KB); B in 16 col-tiles of 32 (16KB); the NEXT
// tile's loads are issued right after the barrier so MFMA+epilogue hide them.
__global__ __launch_bounds__(256) void kv_gemm(
    const float* A, const unsigned short* BT, unsigned short* KVb) {
  __shared__ unsigned short As[64 * 256];   // 32 KB
  __shared__ unsigned short Bs[32 * 256];   // 16 KB
  int t = threadIdx.x;
  int bm = blockIdx.x * 64;
  int w = t >> 6, lane = t & 63;
  int quad = lane >> 4, l16 = lane & 15;
  int wr = w >> 1, wc = w & 1;
  int srow = t >> 2, sub = t & 3;
  // stage A tile once: 64 rows x 256 K, fp32 -> bf16
  {
    const float* Ag = A + (size_t)(bm + srow) * 256 + sub * 64;
#pragma unroll
    for (int i = 0; i < 8; ++i) {
      float4 f0 = *(const float4*)(Ag + i * 8);
      float4 f1 = *(const float4*)(Ag + i * 8 + 4);
      u16x8 u;
      u[0] = f2b(f0.x); u[1] = f2b(f0.y); u[2] = f2b(f0.z); u[3] = f2b(f0.w);
      u[4] = f2b(f1.x); u[5] = f2b(f1.y); u[6] = f2b(f1.z); u[7] = f2b(f1.w);
      *lds_gk<256>(As, srow, sub * 64 + i * 8) = u;
    }
  }
  int brow = t >> 3, bsub = t & 7;  // 32 rows x 8 chunks of 32 for B staging
  u16x8 pre[4];
  {
    const unsigned short* Bg = BT + (size_t)brow * 256 + bsub * 32;
#pragma unroll
    for (int i = 0; i < 4; ++i) pre[i] = *reinterpret_cast<const u16x8*>(Bg + i * 8);
  }
  for (int ct = 0; ct < 16; ++ct) {
#pragma unroll
    for (int i = 0; i < 4; ++i)
      *lds_gk<256>(Bs, brow, bsub * 32 + i * 8) = pre[i];
    __syncthreads();
    if (ct < 15) {  // issue next tile's loads now; latency hidden under MFMA
      const unsigned short* Bg = BT + (size_t)((ct + 1) * 32 + brow) * 256 + bsub * 32;
#pragma unroll
      for (int i = 0; i < 4; ++i) pre[i] = *reinterpret_cast<const u16x8*>(Bg + i * 8);
    }
    f32x4 acc[2];
    acc[0] = (f32x4){0.f, 0.f, 0.f, 0.f};
    acc[1] = (f32x4){0.f, 0.f, 0.f, 0.f};
#pragma unroll
    for (int k = 0; k < 8; ++k) {
      bf16x8 a0 = *reinterpret_cast<bf16x8*>(lds_gk<256>(As, wr * 32 + l16, k * 32 + quad * 8));
      bf16x8 a1 = *reinterpret_cast<bf16x8*>(lds_gk<256>(As, wr * 32 + 16 + l16, k * 32 + quad * 8));
      bf16x8 b0 = *reinterpret_cast<bf16x8*>(lds_gk<256>(Bs, wc * 16 + l16, k * 32 + quad * 8));
      acc[0] = __builtin_amdgcn_mfma_f32_16x16x32_bf16(a0, b0, acc[0], 0, 0, 0);
      acc[1] = __builtin_amdgcn_mfma_f32_16x16x32_bf16(a1, b0, acc[1], 0, 0, 0);
    }
#pragma unroll
    for (int i = 0; i < 2; ++i)
#pragma unroll
      for (int r = 0; r < 4; ++r) {
        int rw = bm + wr * 32 + i * 16 + quad * 4 + r;
        int col = ct * 32 + wc * 16 + l16;
        KVb[(size_t)rw * 512 + col] = f2b(acc[i][r]);
      }
    __syncthreads();  // protect Bs before next restage
  }
}

// ---------------- generic bf16 MFMA GEMM, 64x64 tile, k-step reg prefetch ----
// R0-proven structure (10.2KB LDS -> 8 blocks/CU) + kv_gemm's prefetch trick:
// the NEXT k-step's A/B global loads are issued right after the first barrier,
// so their ~700cy latency overlaps frag reads + MFMA + epilogue + barrier.
// Only the ds_write of already-arrived registers is on the critical path.
template <bool A_FP32, bool COLGRID, bool HAS_BIAS, bool DO_GELU, bool HAS_RESID, bool STORE_F32>
__global__ __launch_bounds__(256) void gemm64(
    const void* Ap, const unsigned short* BT, int M, int N, int K,
    const float* bias, const float* resid, float* outF, unsigned short* outB) {
  __shared__ unsigned short As[64][40];
  __shared__ unsigned short Bs[64][40];
  int t = threadIdx.x;
  int bm = (COLGRID ? blockIdx.x : blockIdx.y) * 64;
  int bn = (COLGRID ? blockIdx.y : blockIdx.x) * 64;
  int w = t >> 6, lane = t & 63;
  int wr = w >> 1, wc = w & 1;
  int quad = lane >> 4, l16 = lane & 15;
  int row = t >> 2, chunk = t & 3;

  const float* AgF = (const float*)Ap + (size_t)(bm + row) * K + chunk * 8;
  const unsigned short* AgB = (const unsigned short*)Ap + (size_t)(bm + row) * K + chunk * 8;
  const unsigned short* Bg = BT + (size_t)(bn + row) * K + chunk * 8;

  float4 pf0, pf1;
  u16x8 pa, pb;
  if (A_FP32) { pf0 = *(const float4*)AgF; pf1 = *(const float4*)(AgF + 4); }
  else        { pa = *(const u16x8*)AgB; }
  pb = *(const u16x8*)Bg;

  f32x4 acc[2][2];
#pragma unroll
  for (int i = 0; i < 2; ++i)
#pragma unroll
    for (int j = 0; j < 2; ++j) acc[i][j] = (f32x4){0.f, 0.f, 0.f, 0.f};

  for (int k0 = 0; k0 < K; k0 += 32) {
    u16x8 ua;
    if (A_FP32) {
      ua[0] = f2b(pf0.x); ua[1] = f2b(pf0.y); ua[2] = f2b(pf0.z); ua[3] = f2b(pf0.w);
      ua[4] = f2b(pf1.x); ua[5] = f2b(pf1.y); ua[6] = f2b(pf1.z); ua[7] = f2b(pf1.w);
    } else {
      ua = pa;
    }
    *reinterpret_cast<u16x8*>(&As[row][chunk * 8]) = ua;
    *reinterpret_cast<u16x8*>(&Bs[row][chunk * 8]) = pb;
    __syncthreads();
    if (k0 + 32 < K) {   // prefetch next k-step while this one computes
      if (A_FP32) { pf0 = *(const float4*)(AgF + k0 + 32); pf1 = *(const float4*)(AgF + k0 + 36); }
      else        { pa = *(const u16x8*)(AgB + k0 + 32); }
      pb = *(const u16x8*)(Bg + k0 + 32);
    }
    bf16x8 a0 = *reinterpret_cast<const bf16x8*>(&As[wr * 32 + l16][quad * 8]);
    bf16x8 a1 = *reinterpret_cast<const bf16x8*>(&As[wr * 32 + 16 + l16][quad * 8]);
    bf16x8 b0 = *reinterpret_cast<const bf16x8*>(&Bs[wc * 32 + l16][quad * 8]);
    bf16x8 b1 = *reinterpret_cast<const bf16x8*>(&Bs[wc * 32 + 16 + l16][quad * 8]);
    acc[0][0] = __builtin_amdgcn_mfma_f32_16x16x32_bf16(a0, b0, acc[0][0], 0, 0, 0);
    acc[0][1] = __builtin_amdgcn_mfma_f32_16x16x32_bf16(a0, b1, acc[0][1], 0, 0, 0);
    acc[1][0] = __builtin_amdgcn_mfma_f32_16x16x32_bf16(a1, b0, acc[1][0], 0, 0, 0);
    acc[1][1] = __builtin_amdgcn_mfma_f32_16x16x32_bf16(a1, b1, acc[1][1], 0, 0, 0);
    __syncthreads();
  }

#pragma unroll
  for (int i = 0; i < 2; ++i)
#pragma unroll
    for (int j = 0; j < 2; ++j) {
      int col = bn + wc * 32 + j * 16 + l16;
      float bv = HAS_BIAS ? bias[col] : 0.f;
#pragma unroll
      for (int r = 0; r < 4; ++r) {
        int rw = bm + wr * 32 + i * 16 + quad * 4 + r;
        float v = acc[i][j][r] + bv;
        if (DO_GELU) v = gelu_f(v);
        if (HAS_RESID) v += resid[(size_t)rw * N + col];
        if (STORE_F32) outF[(size_t)rw * N + col] = v;
        else outB[(size_t)rw * N + col] = f2b(v);
      }
    }
}

// ---------------- edge attention: one wave/query, 4 edges per iteration ------
// 4 edge-slots of 16 lanes each; each lane covers 16 dims (2x u16x8 loads for
// K and V). Halves the serial iteration count vs 2-slot and doubles outstanding
// loads per iteration. Per-head score (HD=32 = 2 lanes) reduces with one
// shfl_xor(1). g is pulled out of the loop: sum alpha*(v+g) = sum alpha*v +
// g*sum(alpha), sum(alpha) = l*em/denom (exact, incl. empty segments).
__global__ __launch_bounds__(256) void attn_edge_kernel(
    const unsigned short* Qb, const unsigned short* Gfb, const unsigned short* KVb,
    const int* s_idx, const int* offs, const float* log_tau, unsigned short* attn_b) {
  int q = blockIdx.x * 4 + (threadIdx.x >> 6);
  int lane = threadIdx.x & 63;
  int slot = lane >> 4;        // which of the 4 edges this lane works on
  int sl = lane & 15;
  int d0 = sl * 16;            // 16 dims per lane
  int e0 = offs[q], e1 = offs[q + 1];
  float invs = expf(-log_tau[0]) * 0.17677669529663687f;  // 1/(sqrt(32)*tau)
  u16x8 qu0 = *(const u16x8*)(Qb + (size_t)q * DN + d0);
  u16x8 qu1 = *(const u16x8*)(Qb + (size_t)q * DN + d0 + 8);
  u16x8 gu0 = *(const u16x8*)(Gfb + (size_t)q * DN + d0);
  u16x8 gu1 = *(const u16x8*)(Gfb + (size_t)q * DN + d0 + 8);
  float qf[16], gf[16];
#pragma unroll
  for (int j = 0; j < 8; ++j) {
    qf[j] = b2f(qu0[j]) * invs; qf[j + 8] = b2f(qu1[j]) * invs;
    gf[j] = b2f(gu0[j]);        gf[j + 8] = b2f(gu1[j]);
  }
  const float NEG = -1e30f;
  float m = -INFINITY, l = 0.f;
  float a[16];
#pragma unroll
  for (int j = 0; j < 16; ++j) a[j] = 0.f;
  for (int e = e0; e < e1; e += 4) {
    int ee = e + slot;
    bool valid = ee < e1;
    int s = s_idx[valid ? ee : (e1 - 1)];
    const unsigned short* kr = KVb + (size_t)s * 512 + d0;
    u16x8 ku0 = *(const u16x8*)kr;
    u16x8 ku1 = *(const u16x8*)(kr + 8);
    u16x8 vu0 = *(const u16x8*)(kr + 256);
    u16x8 vu1 = *(const u16x8*)(kr + 264);
    float p = 0.f;
#pragma unroll
    for (int j = 0; j < 8; ++j) {
      p += qf[j] * b2f(ku0[j]);
      p += qf[j + 8] * b2f(ku1[j]);
    }
    p += __shfl_xor(p, 1);       // head = sl>>1: lanes 2h,2h+1 cover dims 32h..32h+31
    if (!valid) p = -INFINITY;
    float mnew = fmaxf(m, p);
    float sc = (m > NEG) ? __expf(m - mnew) : 0.f;
    float we = valid ? __expf(p - mnew) : 0.f;
    l = l * sc + we;
#pragma unroll
    for (int j = 0; j < 8; ++j) {
      a[j] = a[j] * sc + we * b2f(vu0[j]);
      a[j + 8] = a[j + 8] * sc + we * b2f(vu1[j]);
    }
    m = mnew;
  }
  // merge the 4 slot states (slots 0<->1 / 2<->3, then pairs)
#pragma unroll
  for (int msk = 16; msk <= 32; msk <<= 1) {
    float om = __shfl_xor(m, msk);
    float ol = __shfl_xor(l, msk);
    float M2 = fmaxf(m, om);
    float ws = (m > NEG) ? __expf(m - M2) : 0.f;
    float wo = (om > NEG) ? __expf(om - M2) : 0.f;
    l = l * ws + ol * wo;
#pragma unroll
    for (int j = 0; j < 16; ++j) {
      float oa = __shfl_xor(a[j], msk);
      a[j] = a[j] * ws + oa * wo;
    }
    m = M2;
  }
  // reference: M = max(0, seg_max); denom = max(sum exp(s-M), 1e-8)
  float M = fmaxf(m, 0.f);
  float em = (m > NEG) ? __expf(m - M) : 0.f;
  float denom = fmaxf(l * em, 1e-8f);
  float f = em / denom;
  float sa = l * f;              // = sum(alpha)
  if (slot == 0) {
    u16x8 o0, o1;
#pragma unroll
    for (int j = 0; j < 8; ++j) {
      o0[j] = f2b(a[j] * f + gf[j] * sa);
      o1[j] = f2b(a[j + 8] * f + gf[j + 8] * sa);
    }
    *(u16x8*)(attn_b + (size_t)q * DN + d0) = o0;
    *(u16x8*)(attn_b + (size_t)q * DN + d0 + 8) = o1;
  }
}

extern "C" void kernel_launch(void* const* d_in, const int* in_sizes, int n_in,
                              void* d_out, int out_size, void* d_ws, size_t ws_size,
                              hipStream_t stream) {
  const float* query_tokens  = (const float*)d_in[0];
  const float* query_pos     = (const float*)d_in[1];
  const float* support_feats = (const float*)d_in[2];
  const float* support_pos   = (const float*)d_in[3];
  const float* Wq  = (const float*)d_in[4];
  const float* Wk  = (const float*)d_in[5];
  const float* Wv  = (const float*)d_in[6];
  const float* Wg  = (const float*)d_in[7];
  const float* Wo  = (const float*)d_in[8];
  const float* bo  = (const float*)d_in[9];
  const float* log_tau = (const float*)d_in[10];
  const float* ln1_g = (const float*)d_in[11];
  const float* ln1_b = (const float*)d_in[12];
  const float* ln2_g = (const float*)d_in[13];
  const float* ln2_b = (const float*)d_in[14];
  const float* Wf1 = (const float*)d_in[15];
  const float* bf1 = (const float*)d_in[16];
  const float* Wf2 = (const float*)d_in[17];
  const float* bf2 = (const float*)d_in[18];
  const float* Gw1 = (const float*)d_in[19];
  const float* Gb1 = (const float*)d_in[20];
  const float* Gw2 = (const float*)d_in[21];
  const float* Gb2 = (const float*)d_in[22];
  const int* q_idx = (const int*)d_in[23];
  const int* s_idx = (const int*)d_in[24];
  float* out = (float*)d_out;

  char* ws = (char*)d_ws;
  size_t off = 0;
  auto alloc = [&](size_t bytes) -> void* {
    void* p = ws + off;
    off = (off + bytes + 255) & ~(size_t)255;
    return p;
  };
  unsigned short* WqT  = (unsigned short*)alloc(65536 * 2);
  unsigned short* WkvT = (unsigned short*)alloc(131072 * 2);
  unsigned short* WgT  = (unsigned short*)alloc(32768 * 2);
  unsigned short* WoT  = (unsigned short*)alloc(65536 * 2);
  unsigned short* Wf1T = (unsigned short*)alloc(131072 * 2);
  unsigned short* Wf2T = (unsigned short*)alloc(131072 * 2);
  int* offs            = (int*)alloc((QN + 1) * 4);
  float* raw           = (float*)alloc((size_t)QN * 12 * 4);
  unsigned short* geo_b = (unsigned short*)alloc((size_t)QN * GEON * 2);
  unsigned short* qt_b  = (unsigned short*)alloc((size_t)QN * DN * 2);
  unsigned short* Qb    = (unsigned short*)alloc((size_t)QN * DN * 2);
  unsigned short* Gf_b  = (unsigned short*)alloc((size_t)QN * DN * 2);
  unsigned short* KVb   = (unsigned short*)alloc((size_t)SN * 512 * 2);
  unsigned short* attn_b = (unsigned short*)alloc((size_t)QN * DN * 2);
  float* x1             = (float*)alloc((size_t)QN * DN * 4);
  unsigned short* z_b   = (unsigned short*)alloc((size_t)QN * DN * 2);
  unsigned short* h_b   = (unsigned short*)alloc((size_t)QN * FFNN * 2);

  // 1. weight prep (bf16 transposed copies), tiled/coalesced
  transpose_weights<<<136, 256, 0, stream>>>(Wq, Wk, Wv, Wg, Wo, Wf1, Wf2,
                                             WqT, WkvT, WgT, WoT, Wf1T, Wf2T);
  // 2. segment offsets
  seg_offsets<<<33, 256, 0, stream>>>(q_idx, offs);
  // 3. geo stats
  geo_stats_kernel<<<QN / 64, 256, 0, stream>>>(query_pos, support_pos, offs, s_idx, raw);
  // 4. geo MLP
  geo_mlp_kernel<<<QN / 8, 128, 0, stream>>>(raw, Gw1, Gb1, Gw2, Gb2, geo_b);
  // 5. LN1
  ln_kernel<<<QN / 4, 256, 0, stream>>>(query_tokens, ln1_g, ln1_b, qt_b);
  // 6. KV = support_feats @ [Wk|Wv] — specialized, A staged once
  kv_gemm<<<SN / 64, 256, 0, stream>>>(support_feats, WkvT, KVb);
  // 7. Qf = qt @ Wq, store bf16
  gemm64<false, true, false, false, false, false><<<dim3(QN / 64, DN / 64), 256, 0, stream>>>(
      qt_b, WqT, QN, DN, 256, nullptr, nullptr, nullptr, Qb);
  // 8. Gf = geo @ Wg, store bf16
  gemm64<false, true, false, false, false, false><<<dim3(QN / 64, DN / 64), 256, 0, stream>>>(
      geo_b, WgT, QN, DN, 128, nullptr, nullptr, nullptr, Gf_b);
  // 9. edge attention -> attn_b bf16
  attn_edge_kernel<<<QN / 4, 256, 0, stream>>>(Qb, Gf_b, KVb, s_idx, offs, log_tau, attn_b);
  // 10. x1 = attn @ Wo + bo + query_tokens, store fp32
  gemm64<false, true, true, false, true, true><<<dim3(QN / 64, DN / 64), 256, 0, stream>>>(
      attn_b, WoT, QN, DN, 256, bo, query_tokens, x1, nullptr);
  // 11. LN2
  ln_kernel<<<QN / 4, 256, 0, stream>>>(x1, ln2_g, ln2_b, z_b);
  // 12. h = gelu(z @ Wf1 + bf1), store bf16
  gemm64<false, true, true, true, false, false><<<dim3(QN / 64, FFNN / 64), 256, 0, stream>>>(
      z_b, Wf1T, QN, FFNN, 256, bf1, nullptr, nullptr, h_b);
  // 13. out = h @ Wf2 + bf2 + x1, store fp32 -> d_out
  gemm64<false, true, true, false, true, true><<<dim3(QN / 64, DN / 64), 256, 0, stream>>>(
      h_b, Wf2T, QN, DN, 512, bf2, x1, out, nullptr);

  (void)in_sizes; (void)n_in; (void)out_size; (void)ws_size;
}

// Round 5
// 240.090 us; speedup vs baseline: 1.1497x; 1.0322x over previous
//
#include <hip/hip_runtime.h>
#include <math.h>

#define QN 8192
#define SN 32768
#define EN 131072
#define DN 256
#define HN 8
#define HDN 32
#define GEON 128
#define FFNN 512

typedef __attribute__((ext_vector_type(8))) short bf16x8;
typedef __attribute__((ext_vector_type(8))) unsigned short u16x8;
typedef __attribute__((ext_vector_type(4))) float f32x4;

__device__ __forceinline__ unsigned short f2b(float f) {
  union { float f; unsigned u; } v; v.f = f;
  unsigned u = v.u;
  u += 0x7fffu + ((u >> 16) & 1u);   // round-to-nearest-even
  return (unsigned short)(u >> 16);
}
__device__ __forceinline__ float b2f(unsigned short h) {
  union { unsigned u; float f; } v; v.u = ((unsigned)h) << 16; return v.f;
}
__device__ __forceinline__ float gelu_f(float x) {
  return 0.5f * x * (1.0f + erff(x * 0.70710678118654752440f));
}

// XOR swizzle in 8-element groups: phys_g = g ^ (row&7). Staging writes and
// fragment reads both land at the b128 minimum aliasing (conflict-free).
template <int KT>
__device__ __forceinline__ u16x8* lds_gk(unsigned short* base, int row, int col) {
  int g = (col >> 3) ^ (row & 7);
  return reinterpret_cast<u16x8*>(base + row * KT + g * 8);
}
// scalar u16 store into the same swizzled layout (KT=128)
__device__ __forceinline__ unsigned short* lds_gs128(unsigned short* base, int row, int col) {
  int g = (col >> 3) ^ (row & 7);
  return base + row * 128 + g * 8 + (col & 7);
}

// ================= L1: fused prep = transpose + seg_offsets + LN1 ==========
__global__ __launch_bounds__(256) void fused_prep(
    const float* Wq, const float* Wk, const float* Wv, const float* Wg,
    const float* Wo, const float* Wf1, const float* Wf2,
    unsigned short* WqT, unsigned short* WkvT, unsigned short* WgT,
    unsigned short* WoT, unsigned short* Wf1T, unsigned short* Wf2T,
    const int* q_idx, int* offs,
    const float* x_ln, const float* lng, const float* lnb, unsigned short* ln_out) {
  __shared__ float ts[64][65];
  int b = blockIdx.x;
  int t = threadIdx.x;
  if (b < 136) {
    // ---- weight transpose: fp32 [K,N] -> bf16 [N,K], 64x64 tiles ----
    const float* src; unsigned short* dst; int K, N, tile;
    if (b < 16)       { src = Wq;  dst = WqT;          K = 256; N = 256; tile = b; }
    else if (b < 32)  { src = Wk;  dst = WkvT;         K = 256; N = 256; tile = b - 16; }
    else if (b < 48)  { src = Wv;  dst = WkvT + 65536; K = 256; N = 256; tile = b - 32; }
    else if (b < 56)  { src = Wg;  dst = WgT;          K = 128; N = 256; tile = b - 48; }
    else if (b < 72)  { src = Wo;  dst = WoT;          K = 256; N = 256; tile = b - 56; }
    else if (b < 104) { src = Wf1; dst = Wf1T;         K = 256; N = 512; tile = b - 72; }
    else              { src = Wf2; dst = Wf2T;         K = 512; N = 256; tile = b - 104; }
    int ktiles = K >> 6;
    int k0 = (tile % ktiles) * 64, n0 = (tile / ktiles) * 64;
    int c4 = (t & 15) * 4;
    int r = t >> 4;
#pragma unroll
    for (int p = 0; p < 4; ++p) {
      int row = p * 16 + r;
      float4 v = *(const float4*)(src + (size_t)(k0 + row) * N + n0 + c4);
      ts[row][c4 + 0] = v.x; ts[row][c4 + 1] = v.y;
      ts[row][c4 + 2] = v.z; ts[row][c4 + 3] = v.w;
    }
    __syncthreads();
#pragma unroll
    for (int p = 0; p < 4; ++p) {
      int n = p * 16 + r;
      ushort4 o;
      o.x = f2b(ts[c4 + 0][n]); o.y = f2b(ts[c4 + 1][n]);
      o.z = f2b(ts[c4 + 2][n]); o.w = f2b(ts[c4 + 3][n]);
      *(ushort4*)(dst + (size_t)(n0 + n) * K + k0 + c4) = o;
    }
  } else if (b < 169) {
    // ---- segment offsets: binary search in sorted q_idx ----
    int i = (b - 136) * 256 + t;
    if (i > QN) return;
    int lo = 0, hi = EN;
    while (lo < hi) {
      int mid = (lo + hi) >> 1;
      if (q_idx[mid] < i) lo = mid + 1; else hi = mid;
    }
    offs[i] = lo;
  } else {
    // ---- LN1: fp32 [Q,256] -> bf16, one wave per row ----
    int row = (b - 169) * 4 + (t >> 6);
    int lane = t & 63;
    const float* xr = x_ln + (size_t)row * DN;
    float4 v = *(const float4*)(xr + lane * 4);
    float s = v.x + v.y + v.z + v.w;
    float ss = v.x * v.x + v.y * v.y + v.z * v.z + v.w * v.w;
#pragma unroll
    for (int msk = 1; msk <= 32; msk <<= 1) {
      s += __shfl_xor(s, msk);
      ss += __shfl_xor(ss, msk);
    }
    float mean = s * (1.f / 256.f);
    float var = ss * (1.f / 256.f) - mean * mean;
    float rs = 1.0f / sqrtf(var + 1e-5f);
    float4 gg = *(const float4*)(lng + lane * 4);
    float4 bb = *(const float4*)(lnb + lane * 4);
    unsigned short* o = ln_out + (size_t)row * DN + lane * 4;
    o[0] = f2b((v.x - mean) * rs * gg.x + bb.x);
    o[1] = f2b((v.y - mean) * rs * gg.y + bb.y);
    o[2] = f2b((v.z - mean) * rs * gg.z + bb.z);
    o[3] = f2b((v.w - mean) * rs * gg.w + bb.w);
  }
}

// ---------------- standalone LN (for LN2) ----------------
__global__ __launch_bounds__(256) void ln_kernel(
    const float* x, const float* g, const float* b, unsigned short* out) {
  int row = blockIdx.x * 4 + (threadIdx.x >> 6);
  int lane = threadIdx.x & 63;
  const float* xr = x + (size_t)row * DN;
  float4 v = *(const float4*)(xr + lane * 4);
  float s = v.x + v.y + v.z + v.w;
  float ss = v.x * v.x + v.y * v.y + v.z * v.z + v.w * v.w;
#pragma unroll
  for (int msk = 1; msk <= 32; msk <<= 1) {
    s += __shfl_xor(s, msk);
    ss += __shfl_xor(ss, msk);
  }
  float mean = s * (1.f / 256.f);
  float var = ss * (1.f / 256.f) - mean * mean;
  float rs = 1.0f / sqrtf(var + 1e-5f);
  float4 gg = *(const float4*)(g + lane * 4);
  float4 bb = *(const float4*)(b + lane * 4);
  unsigned short* o = out + (size_t)row * DN + lane * 4;
  o[0] = f2b((v.x - mean) * rs * gg.x + bb.x);
  o[1] = f2b((v.y - mean) * rs * gg.y + bb.y);
  o[2] = f2b((v.z - mean) * rs * gg.z + bb.z);
  o[3] = f2b((v.w - mean) * rs * gg.w + bb.w);
}

// ================= device bodies for fused stage 2 =========================

// ---- KV GEMM body: KV[64 rows, 512] = bf16(fp32 A @ [Wk|Wv]) --------------
// A staged once (32KB); B col-tiles of 32 with register prefetch (16KB).
__device__ __forceinline__ void kv_body(
    char* smem, const float* A, const unsigned short* BT, unsigned short* KVb,
    int bm, int t) {
  unsigned short* As = (unsigned short*)smem;            // 32 KB
  unsigned short* Bs = (unsigned short*)(smem + 32768);  // 16 KB
  int w = t >> 6, lane = t & 63;
  int quad = lane >> 4, l16 = lane & 15;
  int wr = w >> 1, wc = w & 1;
  int srow = t >> 2, sub = t & 3;
  {
    const float* Ag = A + (size_t)(bm + srow) * 256 + sub * 64;
#pragma unroll
    for (int i = 0; i < 8; ++i) {
      float4 f0 = *(const float4*)(Ag + i * 8);
      float4 f1 = *(const float4*)(Ag + i * 8 + 4);
      u16x8 u;
      u[0] = f2b(f0.x); u[1] = f2b(f0.y); u[2] = f2b(f0.z); u[3] = f2b(f0.w);
      u[4] = f2b(f1.x); u[5] = f2b(f1.y); u[6] = f2b(f1.z); u[7] = f2b(f1.w);
      *lds_gk<256>(As, srow, sub * 64 + i * 8) = u;
    }
  }
  int brow = t >> 3, bsub = t & 7;
  u16x8 pre[4];
  {
    const unsigned short* Bg = BT + (size_t)brow * 256 + bsub * 32;
#pragma unroll
    for (int i = 0; i < 4; ++i) pre[i] = *reinterpret_cast<const u16x8*>(Bg + i * 8);
  }
  for (int ct = 0; ct < 16; ++ct) {
#pragma unroll
    for (int i = 0; i < 4; ++i)
      *lds_gk<256>(Bs, brow, bsub * 32 + i * 8) = pre[i];
    __syncthreads();
    if (ct < 15) {
      const unsigned short* Bg = BT + (size_t)((ct + 1) * 32 + brow) * 256 + bsub * 32;
#pragma unroll
      for (int i = 0; i < 4; ++i) pre[i] = *reinterpret_cast<const u16x8*>(Bg + i * 8);
    }
    f32x4 acc[2];
    acc[0] = (f32x4){0.f, 0.f, 0.f, 0.f};
    acc[1] = (f32x4){0.f, 0.f, 0.f, 0.f};
#pragma unroll
    for (int k = 0; k < 8; ++k) {
      bf16x8 a0 = *reinterpret_cast<bf16x8*>(lds_gk<256>(As, wr * 32 + l16, k * 32 + quad * 8));
      bf16x8 a1 = *reinterpret_cast<bf16x8*>(lds_gk<256>(As, wr * 32 + 16 + l16, k * 32 + quad * 8));
      bf16x8 b0 = *reinterpret_cast<bf16x8*>(lds_gk<256>(Bs, wc * 16 + l16, k * 32 + quad * 8));
      acc[0] = __builtin_amdgcn_mfma_f32_16x16x32_bf16(a0, b0, acc[0], 0, 0, 0);
      acc[1] = __builtin_amdgcn_mfma_f32_16x16x32_bf16(a1, b0, acc[1], 0, 0, 0);
    }
#pragma unroll
    for (int i = 0; i < 2; ++i)
#pragma unroll
      for (int r = 0; r < 4; ++r) {
        int rw = bm + wr * 32 + i * 16 + quad * 4 + r;
        int col = ct * 32 + wc * 16 + l16;
        KVb[(size_t)rw * 512 + col] = f2b(acc[i][r]);
      }
    __syncthreads();
  }
}

// ---- gemm64 body: 64x64 tile, 10.2KB LDS, k-step register prefetch --------
template <bool A_FP32, bool HAS_BIAS, bool DO_GELU, bool HAS_RESID, bool STORE_F32>
__device__ __forceinline__ void gemm64_body(
    char* smem, const void* Ap, const unsigned short* BT, int N, int K,
    const float* bias, const float* resid, float* outF, unsigned short* outB,
    int bm, int bn, int t) {
  unsigned short (*As)[40] = (unsigned short(*)[40])smem;
  unsigned short (*Bs)[40] = (unsigned short(*)[40])(smem + 5120);
  int w = t >> 6, lane = t & 63;
  int wr = w >> 1, wc = w & 1;
  int quad = lane >> 4, l16 = lane & 15;
  int row = t >> 2, chunk = t & 3;

  const float* AgF = (const float*)Ap + (size_t)(bm + row) * K + chunk * 8;
  const unsigned short* AgB = (const unsigned short*)Ap + (size_t)(bm + row) * K + chunk * 8;
  const unsigned short* Bg = BT + (size_t)(bn + row) * K + chunk * 8;

  float4 pf0, pf1;
  u16x8 pa, pb;
  if (A_FP32) { pf0 = *(const float4*)AgF; pf1 = *(const float4*)(AgF + 4); }
  else        { pa = *(const u16x8*)AgB; }
  pb = *(const u16x8*)Bg;

  f32x4 acc[2][2];
#pragma unroll
  for (int i = 0; i < 2; ++i)
#pragma unroll
    for (int j = 0; j < 2; ++j) acc[i][j] = (f32x4){0.f, 0.f, 0.f, 0.f};

  for (int k0 = 0; k0 < K; k0 += 32) {
    u16x8 ua;
    if (A_FP32) {
      ua[0] = f2b(pf0.x); ua[1] = f2b(pf0.y); ua[2] = f2b(pf0.z); ua[3] = f2b(pf0.w);
      ua[4] = f2b(pf1.x); ua[5] = f2b(pf1.y); ua[6] = f2b(pf1.z); ua[7] = f2b(pf1.w);
    } else {
      ua = pa;
    }
    *reinterpret_cast<u16x8*>(&As[row][chunk * 8]) = ua;
    *reinterpret_cast<u16x8*>(&Bs[row][chunk * 8]) = pb;
    __syncthreads();
    if (k0 + 32 < K) {
      if (A_FP32) { pf0 = *(const float4*)(AgF + k0 + 32); pf1 = *(const float4*)(AgF + k0 + 36); }
      else        { pa = *(const u16x8*)(AgB + k0 + 32); }
      pb = *(const u16x8*)(Bg + k0 + 32);
    }
    bf16x8 a0 = *reinterpret_cast<const bf16x8*>(&As[wr * 32 + l16][quad * 8]);
    bf16x8 a1 = *reinterpret_cast<const bf16x8*>(&As[wr * 32 + 16 + l16][quad * 8]);
    bf16x8 b0 = *reinterpret_cast<const bf16x8*>(&Bs[wc * 32 + l16][quad * 8]);
    bf16x8 b1 = *reinterpret_cast<const bf16x8*>(&Bs[wc * 32 + 16 + l16][quad * 8]);
    acc[0][0] = __builtin_amdgcn_mfma_f32_16x16x32_bf16(a0, b0, acc[0][0], 0, 0, 0);
    acc[0][1] = __builtin_amdgcn_mfma_f32_16x16x32_bf16(a0, b1, acc[0][1], 0, 0, 0);
    acc[1][0] = __builtin_amdgcn_mfma_f32_16x16x32_bf16(a1, b0, acc[1][0], 0, 0, 0);
    acc[1][1] = __builtin_amdgcn_mfma_f32_16x16x32_bf16(a1, b1, acc[1][1], 0, 0, 0);
    __syncthreads();
  }

#pragma unroll
  for (int i = 0; i < 2; ++i)
#pragma unroll
    for (int j = 0; j < 2; ++j) {
      int col = bn + wc * 32 + j * 16 + l16;
      float bv = HAS_BIAS ? bias[col] : 0.f;
#pragma unroll
      for (int r = 0; r < 4; ++r) {
        int rw = bm + wr * 32 + i * 16 + quad * 4 + r;
        float v = acc[i][j][r] + bv;
        if (DO_GELU) v = gelu_f(v);
        if (HAS_RESID) v += resid[(size_t)rw * N + col];
        if (STORE_F32) outF[(size_t)rw * N + col] = v;
        else outB[(size_t)rw * N + col] = f2b(v);
      }
    }
}

// ---- geo mega body: stats -> MLP -> Gf GEMM, 64 queries per block ---------
// smem layout: [0,3072) rs f32[64][12]; [3072,19456) geo bf16 swizzled [64][128];
// [19456,52224) h1 f32[64][128]  (aliased by Bs bf16[64][128] in phase 3).
__device__ __forceinline__ void geo_body(
    char* smem, const float* qpos, const float* spos, const int* offs,
    const int* s_idx, const float* Gw1, const float* Gb1,
    const float* Gw2, const float* Gb2, const unsigned short* WgT,
    unsigned short* Gf_b, int qb, int t) {
  float (*rs)[12] = (float(*)[12])smem;
  unsigned short* geoL = (unsigned short*)(smem + 3072);
  float (*h1)[128] = (float(*)[128])(smem + 19456);
  unsigned short* Bs = (unsigned short*)(smem + 19456);

  // ---- phase 1: stats (4 lanes per query) ----
  {
    int q = qb + (t >> 2);
    int sub = t & 3;
    int e0 = offs[q], e1 = offs[q + 1];
    float qx = qpos[q * 3 + 0], qy = qpos[q * 3 + 1], qz = qpos[q * 3 + 2];
    float cnt = 0.f, sx = 0.f, sy = 0.f, sz = 0.f, sxx = 0.f, syy = 0.f, szz = 0.f;
    float mnx = 1e30f, mny = 1e30f, mnz = 1e30f, mxx = -1e30f, mxy = -1e30f, mxz = -1e30f;
    for (int e = e0 + sub; e < e1; e += 4) {
      int s = s_idx[e];
      float rx = spos[s * 3 + 0] - qx;
      float ry = spos[s * 3 + 1] - qy;
      float rz = spos[s * 3 + 2] - qz;
      cnt += 1.f;
      sx += rx; sy += ry; sz += rz;
      sxx += rx * rx; syy += ry * ry; szz += rz * rz;
      mnx = fminf(mnx, rx); mny = fminf(mny, ry); mnz = fminf(mnz, rz);
      mxx = fmaxf(mxx, rx); mxy = fmaxf(mxy, ry); mxz = fmaxf(mxz, rz);
    }
#pragma unroll
    for (int msk = 1; msk <= 2; msk <<= 1) {
      cnt += __shfl_xor(cnt, msk);
      sx += __shfl_xor(sx, msk); sy += __shfl_xor(sy, msk); sz += __shfl_xor(sz, msk);
      sxx += __shfl_xor(sxx, msk); syy += __shfl_xor(syy, msk); szz += __shfl_xor(szz, msk);
      mnx = fminf(mnx, __shfl_xor(mnx, msk));
      mny = fminf(mny, __shfl_xor(mny, msk));
      mnz = fminf(mnz, __shfl_xor(mnz, msk));
      mxx = fmaxf(mxx, __shfl_xor(mxx, msk));
      mxy = fmaxf(mxy, __shfl_xor(mxy, msk));
      mxz = fmaxf(mxz, __shfl_xor(mxz, msk));
    }
    if (sub == 0) {
      int qq = t >> 2;
      float c = fmaxf(cnt, 1.f);
      float mx_ = sx / c, my_ = sy / c, mz_ = sz / c;
      float vx = fmaxf(sxx / c - mx_ * mx_, 0.f);
      float vy = fmaxf(syy / c - my_ * my_, 0.f);
      float vz = fmaxf(szz / c - mz_ * mz_, 0.f);
      rs[qq][0] = mx_; rs[qq][1] = my_; rs[qq][2] = mz_;
      rs[qq][3] = sqrtf(vx); rs[qq][4] = sqrtf(vy); rs[qq][5] = sqrtf(vz);
      rs[qq][6] = fminf(fmaxf(mnx, -100.f), 100.f);
      rs[qq][7] = fminf(fmaxf(mny, -100.f), 100.f);
      rs[qq][8] = fminf(fmaxf(mnz, -100.f), 100.f);
      rs[qq][9] = fminf(fmaxf(mxx, -100.f), 100.f);
      rs[qq][10] = fminf(fmaxf(mxy, -100.f), 100.f);
      rs[qq][11] = fminf(fmaxf(mxz, -100.f), 100.f);
    }
  }
  __syncthreads();

  // ---- phase 2: MLP. thread = (dim j, query-group grp of 32) ----
  {
    int j = t & 127;
    int grp = t >> 7;
    int qbase = grp * 32;
    float acc[32];
    float b1 = Gb1[j];
#pragma unroll
    for (int qq = 0; qq < 32; ++qq) acc[qq] = b1;
    for (int i = 0; i < 12; ++i) {
      float wv = Gw1[i * GEON + j];
#pragma unroll
      for (int qq = 0; qq < 32; ++qq) acc[qq] += rs[qbase + qq][i] * wv;
    }
#pragma unroll
    for (int qq = 0; qq < 32; ++qq) h1[qbase + qq][j] = gelu_f(acc[qq]);
    __syncthreads();
    float b2 = Gb2[j];
    float acc2[32];
#pragma unroll
    for (int qq = 0; qq < 32; ++qq) acc2[qq] = b2;
    for (int k = 0; k < 128; ++k) {
      float wv = Gw2[k * GEON + j];
#pragma unroll
      for (int qq = 0; qq < 32; ++qq) acc2[qq] += h1[qbase + qq][k] * wv;
    }
    // write geo (bf16, swizzled) — region disjoint from h1
#pragma unroll
    for (int qq = 0; qq < 32; ++qq)
      *lds_gs128(geoL, qbase + qq, j) = f2b(gelu_f(acc2[qq]));
  }
  __syncthreads();   // geo visible; h1 dead -> Bs may overwrite

  // ---- phase 3: Gf[qb..qb+63, 0..255] = geo @ Wg via MFMA ----
  {
    int w = t >> 6, lane = t & 63;
    int wr = w >> 1, wc = w & 1;
    int quad = lane >> 4, l16 = lane & 15;
    int row = t >> 2, sub = t & 3;
    for (int ct = 0; ct < 4; ++ct) {
      int bn = ct * 64;
      {
        const unsigned short* Bg = WgT + (size_t)(bn + row) * 128 + sub * 32;
#pragma unroll
        for (int i = 0; i < 4; ++i)
          *lds_gk<128>(Bs, row, sub * 32 + i * 8) = *reinterpret_cast<const u16x8*>(Bg + i * 8);
      }
      __syncthreads();
      f32x4 acc[2][2];
#pragma unroll
      for (int i = 0; i < 2; ++i)
#pragma unroll
        for (int j = 0; j < 2; ++j) acc[i][j] = (f32x4){0.f, 0.f, 0.f, 0.f};
#pragma unroll
      for (int k = 0; k < 4; ++k) {
        bf16x8 a0 = *reinterpret_cast<bf16x8*>(lds_gk<128>(geoL, wr * 32 + l16, k * 32 + quad * 8));
        bf16x8 a1 = *reinterpret_cast<bf16x8*>(lds_gk<128>(geoL, wr * 32 + 16 + l16, k * 32 + quad * 8));
        bf16x8 b0 = *reinterpret_cast<bf16x8*>(lds_gk<128>(Bs, wc * 32 + l16, k * 32 + quad * 8));
        bf16x8 b1 = *reinterpret_cast<bf16x8*>(lds_gk<128>(Bs, wc * 32 + 16 + l16, k * 32 + quad * 8));
        acc[0][0] = __builtin_amdgcn_mfma_f32_16x16x32_bf16(a0, b0, acc[0][0], 0, 0, 0);
        acc[0][1] = __builtin_amdgcn_mfma_f32_16x16x32_bf16(a0, b1, acc[0][1], 0, 0, 0);
        acc[1][0] = __builtin_amdgcn_mfma_f32_16x16x32_bf16(a1, b0, acc[1][0], 0, 0, 0);
        acc[1][1] = __builtin_amdgcn_mfma_f32_16x16x32_bf16(a1, b1, acc[1][1], 0, 0, 0);
      }
#pragma unroll
      for (int i = 0; i < 2; ++i)
#pragma unroll
        for (int j = 0; j < 2; ++j) {
          int col = bn + wc * 32 + j * 16 + l16;
#pragma unroll
          for (int r = 0; r < 4; ++r) {
            int rw = qb + wr * 32 + i * 16 + quad * 4 + r;
            Gf_b[(size_t)rw * 256 + col] = f2b(acc[i][j][r]);
          }
        }
      __syncthreads();
    }
  }
}

// ================= L2: fused stage 2 = geo-mega + kv + Qf ==================
__global__ __launch_bounds__(256) void fused_stage2(
    const float* qpos, const float* spos, const int* offs, const int* s_idx,
    const float* Gw1, const float* Gb1, const float* Gw2, const float* Gb2,
    const unsigned short* WgT, unsigned short* Gf_b,
    const float* support_feats, const unsigned short* WkvT, unsigned short* KVb,
    const unsigned short* qt_b, const unsigned short* WqT, unsigned short* Qb) {
  __shared__ __align__(16) char smem[52224];
  int b = blockIdx.x;
  int t = threadIdx.x;
  if (b < 128) {
    geo_body(smem, qpos, spos, offs, s_idx, Gw1, Gb1, Gw2, Gb2, WgT, Gf_b, b * 64, t);
  } else if (b < 640) {
    kv_body(smem, support_feats, WkvT, KVb, (b - 128) * 64, t);
  } else {
    int bb = b - 640;
    int bm = (bb & 127) * 64, bn = (bb >> 7) * 64;
    gemm64_body<false, false, false, false, false>(
        smem, qt_b, WqT, DN, 256, nullptr, nullptr, nullptr, Qb, bm, bn, t);
  }
}

// ---------------- standalone gemm64 wrapper (Wo, FFN1, FFN2) ---------------
template <bool A_FP32, bool HAS_BIAS, bool DO_GELU, bool HAS_RESID, bool STORE_F32>
__global__ __launch_bounds__(256) void gemm64(
    const void* Ap, const unsigned short* BT, int N, int K,
    const float* bias, const float* resid, float* outF, unsigned short* outB) {
  __shared__ __align__(16) char smem[10240];
  gemm64_body<A_FP32, HAS_BIAS, DO_GELU, HAS_RESID, STORE_F32>(
      smem, Ap, BT, N, K, bias, resid, outF, outB,
      blockIdx.x * 64, blockIdx.y * 64, threadIdx.x);
}

// ---------------- edge attention: one wave/query, 4 edges per iteration ----
__global__ __launch_bounds__(256) void attn_edge_kernel(
    const unsigned short* Qb, const unsigned short* Gfb, const unsigned short* KVb,
    const int* s_idx, const int* offs, const float* log_tau, unsigned short* attn_b) {
  int q = blockIdx.x * 4 + (threadIdx.x >> 6);
  int lane = threadIdx.x & 63;
  int slot = lane >> 4;
  int sl = lane & 15;
  int d0 = sl * 16;
  int e0 = offs[q], e1 = offs[q + 1];
  float invs = expf(-log_tau[0]) * 0.17677669529663687f;  // 1/(sqrt(32)*tau)
  u16x8 qu0 = *(const u16x8*)(Qb + (size_t)q * DN + d0);
  u16x8 qu1 = *(const u16x8*)(Qb + (size_t)q * DN + d0 + 8);
  u16x8 gu0 = *(const u16x8*)(Gfb + (size_t)q * DN + d0);
  u16x8 gu1 = *(const u16x8*)(Gfb + (size_t)q * DN + d0 + 8);
  float qf[16], gf[16];
#pragma unroll
  for (int j = 0; j < 8; ++j) {
    qf[j] = b2f(qu0[j]) * invs; qf[j + 8] = b2f(qu1[j]) * invs;
    gf[j] = b2f(gu0[j]);        gf[j + 8] = b2f(gu1[j]);
  }
  const float NEG = -1e30f;
  float m = -INFINITY, l = 0.f;
  float a[16];
#pragma unroll
  for (int j = 0; j < 16; ++j) a[j] = 0.f;
  for (int e = e0; e < e1; e += 4) {
    int ee = e + slot;
    bool valid = ee < e1;
    int s = s_idx[valid ? ee : (e1 - 1)];
    const unsigned short* kr = KVb + (size_t)s * 512 + d0;
    u16x8 ku0 = *(const u16x8*)kr;
    u16x8 ku1 = *(const u16x8*)(kr + 8);
    u16x8 vu0 = *(const u16x8*)(kr + 256);
    u16x8 vu1 = *(const u16x8*)(kr + 264);
    float p = 0.f;
#pragma unroll
    for (int j = 0; j < 8; ++j) {
      p += qf[j] * b2f(ku0[j]);
      p += qf[j + 8] * b2f(ku1[j]);
    }
    p += __shfl_xor(p, 1);
    if (!valid) p = -INFINITY;
    float mnew = fmaxf(m, p);
    float sc = (m > NEG) ? __expf(m - mnew) : 0.f;
    float we = valid ? __expf(p - mnew) : 0.f;
    l = l * sc + we;
#pragma unroll
    for (int j = 0; j < 8; ++j) {
      a[j] = a[j] * sc + we * b2f(vu0[j]);
      a[j + 8] = a[j + 8] * sc + we * b2f(vu1[j]);
    }
    m = mnew;
  }
#pragma unroll
  for (int msk = 16; msk <= 32; msk <<= 1) {
    float om = __shfl_xor(m, msk);
    float ol = __shfl_xor(l, msk);
    float M2 = fmaxf(m, om);
    float ws = (m > NEG) ? __expf(m - M2) : 0.f;
    float wo = (om > NEG) ? __expf(om - M2) : 0.f;
    l = l * ws + ol * wo;
#pragma unroll
    for (int j = 0; j < 16; ++j) {
      float oa = __shfl_xor(a[j], msk);
      a[j] = a[j] * ws + oa * wo;
    }
    m = M2;
  }
  float M = fmaxf(m, 0.f);
  float em = (m > NEG) ? __expf(m - M) : 0.f;
  float denom = fmaxf(l * em, 1e-8f);
  float f = em / denom;
  float sa = l * f;              // = sum(alpha)
  if (slot == 0) {
    u16x8 o0, o1;
#pragma unroll
    for (int j = 0; j < 8; ++j) {
      o0[j] = f2b(a[j] * f + gf[j] * sa);
      o1[j] = f2b(a[j + 8] * f + gf[j + 8] * sa);
    }
    *(u16x8*)(attn_b + (size_t)q * DN + d0) = o0;
    *(u16x8*)(attn_b + (size_t)q * DN + d0 + 8) = o1;
  }
}

extern "C" void kernel_launch(void* const* d_in, const int* in_sizes, int n_in,
                              void* d_out, int out_size, void* d_ws, size_t ws_size,
                              hipStream_t stream) {
  const float* query_tokens  = (const float*)d_in[0];
  const float* query_pos     = (const float*)d_in[1];
  const float* support_feats = (const float*)d_in[2];
  const float* support_pos   = (const float*)d_in[3];
  const float* Wq  = (const float*)d_in[4];
  const float* Wk  = (const float*)d_in[5];
  const float* Wv  = (const float*)d_in[6];
  const float* Wg  = (const float*)d_in[7];
  const float* Wo  = (const float*)d_in[8];
  const float* bo  = (const float*)d_in[9];
  const float* log_tau = (const float*)d_in[10];
  const float* ln1_g = (const float*)d_in[11];
  const float* ln1_b = (const float*)d_in[12];
  const float* ln2_g = (const float*)d_in[13];
  const float* ln2_b = (const float*)d_in[14];
  const float* Wf1 = (const float*)d_in[15];
  const float* bf1 = (const float*)d_in[16];
  const float* Wf2 = (const float*)d_in[17];
  const float* bf2 = (const float*)d_in[18];
  const float* Gw1 = (const float*)d_in[19];
  const float* Gb1 = (const float*)d_in[20];
  const float* Gw2 = (const float*)d_in[21];
  const float* Gb2 = (const float*)d_in[22];
  const int* q_idx = (const int*)d_in[23];
  const int* s_idx = (const int*)d_in[24];
  float* out = (float*)d_out;

  char* ws = (char*)d_ws;
  size_t off = 0;
  auto alloc = [&](size_t bytes) -> void* {
    void* p = ws + off;
    off = (off + bytes + 255) & ~(size_t)255;
    return p;
  };
  unsigned short* WqT  = (unsigned short*)alloc(65536 * 2);
  unsigned short* WkvT = (unsigned short*)alloc(131072 * 2);
  unsigned short* WgT  = (unsigned short*)alloc(32768 * 2);
  unsigned short* WoT  = (unsigned short*)alloc(65536 * 2);
  unsigned short* Wf1T = (unsigned short*)alloc(131072 * 2);
  unsigned short* Wf2T = (unsigned short*)alloc(131072 * 2);
  int* offs            = (int*)alloc((QN + 1) * 4);
  unsigned short* qt_b  = (unsigned short*)alloc((size_t)QN * DN * 2);
  unsigned short* Qb    = (unsigned short*)alloc((size_t)QN * DN * 2);
  unsigned short* Gf_b  = (unsigned short*)alloc((size_t)QN * DN * 2);
  unsigned short* KVb   = (unsigned short*)alloc((size_t)SN * 512 * 2);
  unsigned short* attn_b = (unsigned short*)alloc((size_t)QN * DN * 2);
  float* x1             = (float*)alloc((size_t)QN * DN * 4);
  unsigned short* z_b   = (unsigned short*)alloc((size_t)QN * DN * 2);
  unsigned short* h_b   = (unsigned short*)alloc((size_t)QN * FFNN * 2);

  // L1: weight transpose + segment offsets + LN1  (input-only deps)
  fused_prep<<<2217, 256, 0, stream>>>(Wq, Wk, Wv, Wg, Wo, Wf1, Wf2,
                                       WqT, WkvT, WgT, WoT, Wf1T, Wf2T,
                                       q_idx, offs,
                                       query_tokens, ln1_g, ln1_b, qt_b);
  // L2: geo(stats->MLP->Gf) + KV gemm + Qf gemm  (co-scheduled)
  fused_stage2<<<1152, 256, 0, stream>>>(query_pos, support_pos, offs, s_idx,
                                         Gw1, Gb1, Gw2, Gb2, WgT, Gf_b,
                                         support_feats, WkvT, KVb,
                                         qt_b, WqT, Qb);
  // L3: edge attention -> attn_b bf16
  attn_edge_kernel<<<QN / 4, 256, 0, stream>>>(Qb, Gf_b, KVb, s_idx, offs, log_tau, attn_b);
  // L4: x1 = attn @ Wo + bo + query_tokens, store fp32
  gemm64<false, true, false, true, true><<<dim3(QN / 64, DN / 64), 256, 0, stream>>>(
      attn_b, WoT, DN, 256, bo, query_tokens, x1, nullptr);
  // L5: LN2
  ln_kernel<<<QN / 4, 256, 0, stream>>>(x1, ln2_g, ln2_b, z_b);
  // L6: h = gelu(z @ Wf1 + bf1), store bf16
  gemm64<false, true, true, false, false><<<dim3(QN / 64, FFNN / 64), 256, 0, stream>>>(
      z_b, Wf1T, FFNN, 256, bf1, nullptr, nullptr, h_b);
  // L7: out = h @ Wf2 + bf2 + x1, store fp32 -> d_out
  gemm64<false, true, false, true, true><<<dim3(QN / 64, DN / 64), 256, 0, stream>>>(
      h_b, Wf2T, DN, 512, bf2, x1, out, nullptr);

  (void)in_sizes; (void)n_in; (void)out_size; (void)ws_size;
}